// Round 1
// baseline (209.643 us; speedup 1.0000x reference)
//
#include <hip/hip_runtime.h>

#define B_ 64
#define N_ 4096
#define C_ 10
#define D_ 8
#define E_ 16
#define EPS_ 1e-7f

__device__ inline float reduce16(float v) {
    v += __shfl_xor(v, 1);
    v += __shfl_xor(v, 2);
    v += __shfl_xor(v, 4);
    v += __shfl_xor(v, 8);
    return v;
}

// One block: one b, one chunk of npb n-values. 16 lanes per n (lane = e).
__global__ __launch_bounds__(256) void caps_pass(
    const float* __restrict__ x, const float* __restrict__ W,
    const float* __restrict__ v_cum, float* __restrict__ partial_s,
    int nchunk, int npb)
{
    const int b = blockIdx.x;
    const int chunk = blockIdx.y;
    const int tid = (int)threadIdx.x;
    const int group = tid >> 4;   // 16 groups of 16 lanes
    const int le = tid & 15;      // lane's e index

    // per-lane slice of cumulative v: vc[c] = v_cum[b,c,le]
    float vc[C_];
#pragma unroll
    for (int c = 0; c < C_; ++c) vc[c] = v_cum[(b * C_ + c) * E_ + le];

    float acc[C_];
#pragma unroll
    for (int c = 0; c < C_; ++c) acc[c] = 0.f;

    for (int i = group; i < npb; i += 16) {
        const int n = chunk * npb + i;
        const float* xp = x + ((size_t)b * N_ + n) * D_;
        float xv[D_];
#pragma unroll
        for (int d = 0; d < D_; ++d) xv[d] = xp[d];

        const float* Wn = W + (size_t)n * (C_ * D_ * E_);
        float uh[C_];
#pragma unroll
        for (int c = 0; c < C_; ++c) {
            float u = 0.f;
#pragma unroll
            for (int d = 0; d < D_; ++d)
                u = fmaf(xv[d], Wn[c * (D_ * E_) + d * E_ + le], u);
            uh[c] = u;
        }

        // logits[c] = sum_e uh[c][e] * v_cum[b,c,e]  (16-lane reduce)
        float logit[C_];
#pragma unroll
        for (int c = 0; c < C_; ++c) logit[c] = reduce16(uh[c] * vc[c]);

        // softmax over C (identical in all 16 lanes of the group)
        float m = logit[0];
#pragma unroll
        for (int c = 1; c < C_; ++c) m = fmaxf(m, logit[c]);
        float ssum = 0.f;
        float ec[C_];
#pragma unroll
        for (int c = 0; c < C_; ++c) { ec[c] = __expf(logit[c] - m); ssum += ec[c]; }
        const float inv = 1.f / ssum;
#pragma unroll
        for (int c = 0; c < C_; ++c) acc[c] = fmaf(ec[c] * inv, uh[c], acc[c]);
    }

    // block reduce over the 16 groups
    __shared__ float lds[16][C_][E_];
#pragma unroll
    for (int c = 0; c < C_; ++c) lds[group][c][le] = acc[c];
    __syncthreads();
    if (tid < C_ * E_) {
        const int c = tid >> 4;
        const int e = tid & 15;
        float s = 0.f;
#pragma unroll
        for (int g = 0; g < 16; ++g) s += lds[g][c][e];
        partial_s[(((size_t)b * nchunk + chunk) * C_ + c) * E_ + e] = s;
    }
}

// One block per b: sum partials over chunks, squash, update v_cum or write out.
__global__ __launch_bounds__(192) void caps_reduce(
    const float* __restrict__ partial_s, float* __restrict__ v_cum,
    float* __restrict__ out, int nchunk, int last)
{
    const int b = blockIdx.x;
    const int tid = (int)threadIdx.x;
    if (tid >= C_ * E_) return;
    const int c = tid >> 4;
    const int e = tid & 15;
    float s = 0.f;
    for (int k = 0; k < nchunk; ++k)
        s += partial_s[(((size_t)b * nchunk + k) * C_ + c) * E_ + e];
    const float s2 = reduce16(s * s);
    const float scale = (s2 / (1.f + s2)) * rsqrtf(s2 + EPS_);
    const float v = scale * s;
    if (last) out[(b * C_ + c) * E_ + e] = v;
    else      v_cum[(b * C_ + c) * E_ + e] += v;
}

extern "C" void kernel_launch(void* const* d_in, const int* in_sizes, int n_in,
                              void* d_out, int out_size, void* d_ws, size_t ws_size,
                              hipStream_t stream) {
    const float* x = (const float*)d_in[0];
    const float* W = (const float*)d_in[1];
    float* out = (float*)d_out;

    const size_t vbytes = (size_t)B_ * C_ * E_ * sizeof(float);  // 40 KB
    float* v_cum = (float*)d_ws;
    float* partial = (float*)((char*)d_ws + vbytes);

    int nchunk = 32;
    while (nchunk > 1 &&
           vbytes + (size_t)B_ * nchunk * C_ * E_ * sizeof(float) > ws_size)
        nchunk >>= 1;
    const int npb = N_ / nchunk;

    hipMemsetAsync(v_cum, 0, vbytes, stream);
    for (int t = 0; t < 3; ++t) {
        dim3 grid(B_, nchunk);
        caps_pass<<<grid, 256, 0, stream>>>(x, W, v_cum, partial, nchunk, npb);
        caps_reduce<<<B_, 192, 0, stream>>>(partial, v_cum, out, nchunk, t == 2);
    }
}